// Round 1
// baseline (961.756 us; speedup 1.0000x reference)
//
#include <hip/hip_runtime.h>

// Problem constants (from reference setup_inputs):
//   x:        (32, 3, 1024, 1024) f32  -- UNUSED by the math (masks depend only on initmask)
//   initmask: (32, 1, 512, 512)   int  -- values 0..3
// Outputs: mask1, mask2 each (32,3,1024,1024) f32, concatenated in d_out.
//
// full-res (r, col) value = PATTERNS[initmask[b, r/2, col/2]][r&1][col&1]
// PATTERNS packed 2 bits/value, 8 bits/pattern, pos = di*2+dj:
//   p0: 1,2,0,0 -> 0x09 ; p1: 0,1,0,2 -> 0x84 ; p2: 0,0,2,1 -> 0x60 ; p3: 2,0,1,0 -> 0x12
//   PACK = 0x12608409

#define BB 32
#define CC 3
#define WW 1024
#define HH 1024
#define WM (WW / 2)      // 512 mask rows
#define HM (HH / 2)      // 512 mask cols
#define J2 (HM / 2)      // 256 int2 groups per mask row

__global__ __launch_bounds__(256) void masksampling_kernel(const int* __restrict__ im,
                                                           float* __restrict__ out) {
    // One thread per (b, i, j2): a 2x2-cell-pair = 4 full cols x 2 full rows block.
    const unsigned tid = blockIdx.x * 256u + threadIdx.x;   // 32*512*256 = 4,194,304 total
    const unsigned j2 = tid & (J2 - 1);          // 0..255
    const unsigned i  = (tid >> 8) & (WM - 1);   // 0..511
    const unsigned b  = tid >> 17;               // 0..31

    const int2 m2 = ((const int2*)im)[(b * WM + i) * J2 + j2];
    const unsigned PACK = 0x12608409u;
    const unsigned s0 = (unsigned)m2.x * 8u;
    const unsigned s1 = (unsigned)m2.y * 8u;

    float4* out1 = (float4*)out;
    float4* out2 = out1 + (BB * CC * WW * HH) / 4;   // 50,331,648 float4s

    #pragma unroll
    for (int di = 0; di < 2; ++di) {
        const unsigned v0 = (PACK >> (s0 + di * 4 + 0)) & 3u;
        const unsigned v1 = (PACK >> (s0 + di * 4 + 2)) & 3u;
        const unsigned v2 = (PACK >> (s1 + di * 4 + 0)) & 3u;
        const unsigned v3 = (PACK >> (s1 + di * 4 + 2)) & 3u;
        const float4 f1 = make_float4(v0 == 1u ? 1.f : 0.f, v1 == 1u ? 1.f : 0.f,
                                      v2 == 1u ? 1.f : 0.f, v3 == 1u ? 1.f : 0.f);
        const float4 f2 = make_float4(v0 == 2u ? 1.f : 0.f, v1 == 2u ? 1.f : 0.f,
                                      v2 == 2u ? 1.f : 0.f, v3 == 2u ? 1.f : 0.f);
        const unsigned r = 2u * i + (unsigned)di;
        #pragma unroll
        for (int c = 0; c < CC; ++c) {
            // float4 index: (((b*3 + c)*1024 + r)*1024 + 4*j2) / 4
            const unsigned off = ((b * CC + c) * WW + r) * (HH / 4) + j2;
            out1[off] = f1;
            out2[off] = f2;
        }
    }
}

extern "C" void kernel_launch(void* const* d_in, const int* in_sizes, int n_in,
                              void* d_out, int out_size, void* d_ws, size_t ws_size,
                              hipStream_t stream) {
    // d_in[0] = x (unused), d_in[1] = initmask (int32 per harness convention)
    const int* im = (const int*)d_in[1];
    float* out = (float*)d_out;
    const int total = BB * WM * J2;            // 4,194,304 threads
    masksampling_kernel<<<total / 256, 256, 0, stream>>>(im, out);
}

// Round 2
// 940.649 us; speedup vs baseline: 1.0224x; 1.0224x over previous
//
#include <hip/hip_runtime.h>

// masksampling: outputs depend ONLY on initmask (x unused).
//   initmask: (32, 1, 512, 512) int (0..3)
//   out: mask1, mask2 each (32,3,1024,1024) f32, concatenated.
//
// full-res (r,col) value = PATTERNS[m][r&1][col&1], m = initmask[b, r>>1, col>>1]
// Equality LUTs, bit index = m*4 + (r&1)*2 + (col&1):
//   EQ1 (val==1) = 0x4821, EQ2 (val==2) = 0x1482
//
// Linear mapping: thread t owns float4 index t of EACH output (2 streams,
// perfectly sequential across the grid — matches fillBuffer's 6.3 TB/s pattern).

#define N_F4_PER_OUT 25165824u   // 32*3*1024*1024/4

__global__ __launch_bounds__(256) void masksampling_kernel(const int* __restrict__ im,
                                                           float* __restrict__ out) {
    const unsigned t = blockIdx.x * 256u + threadIdx.x;   // 0 .. 25,165,823
    const unsigned j  = t & 255u;           // col group of 4 (cols 4j..4j+3)
    const unsigned r  = (t >> 8) & 1023u;   // full-res row
    const unsigned bc = t >> 18;            // (b*3 + c), 0..95
    const unsigned b  = bc / 3u;            // magic-mul by compiler

    // mask int2 index: (b*512 + r/2)*256 + j  (cells 2j, 2j+1 of mask row r/2)
    const int2 m2 = ((const int2*)im)[b * 131072u + (r >> 1) * 256u + j];

    const unsigned base = (r & 1u) * 2u;
    const unsigned s0 = (unsigned)m2.x * 4u + base;   // cols 4j, 4j+1
    const unsigned s1 = (unsigned)m2.y * 4u + base;   // cols 4j+2, 4j+3

    const unsigned EQ1 = 0x4821u, EQ2 = 0x1482u;
    const float4 f1 = make_float4((float)((EQ1 >> s0) & 1u),
                                  (float)((EQ1 >> (s0 + 1u)) & 1u),
                                  (float)((EQ1 >> s1) & 1u),
                                  (float)((EQ1 >> (s1 + 1u)) & 1u));
    const float4 f2 = make_float4((float)((EQ2 >> s0) & 1u),
                                  (float)((EQ2 >> (s0 + 1u)) & 1u),
                                  (float)((EQ2 >> s1) & 1u),
                                  (float)((EQ2 >> (s1 + 1u)) & 1u));

    float4* o1 = (float4*)out;
    float4* o2 = o1 + N_F4_PER_OUT;
    o1[t] = f1;
    o2[t] = f2;
}

extern "C" void kernel_launch(void* const* d_in, const int* in_sizes, int n_in,
                              void* d_out, int out_size, void* d_ws, size_t ws_size,
                              hipStream_t stream) {
    const int* im = (const int*)d_in[1];   // d_in[0] = x (unused)
    float* out = (float*)d_out;
    masksampling_kernel<<<N_F4_PER_OUT / 256, 256, 0, stream>>>(im, out);
}